// Round 12
// baseline (270.690 us; speedup 1.0000x reference)
//
#include <hip/hip_runtime.h>

#define B_ 4
#define S_ 2
#define C_ 6
#define F_ 512
#define N_ 2000
#define CH_ (F_ * N_)          // stride between channels / mask slices
#define LOAD_CONST 1e-5
#define EPS_DENOM_ 1e-6
#define NV4 (N_ / 4)           // 500 float4 per stream
#define NCHUNK 8

// ---------------------------------------------------------------------------
// Kernel 1: masked covariances — 2-wave blocks share X via LDS.
// r9/r10/r11 post-mortem: three structures, one number (~150us). All move
// 1.28 GB through the L2->CU path (X read once PER SET) at a measured
// ~14 B/cy/CU path rate. TLP saturated (doubling waves: no change). The
// remaining lever is PATH BYTES: block=(bf,i), wave s computes set j=s*3+i,
// X staged ONCE per block via global_load_lds -> 688 MB instead of 1.28 GB.
// 3-buffer pipeline, counted vmcnt(7) (T4), 2-wave barrier.
// XCD-bijective swizzle keeps the 3 i-blocks of a (b,f) on one XCD (r9).
// ---------------------------------------------------------------------------
__device__ __forceinline__ void gld_lds16(const void* gp, void* lp) {
  __builtin_amdgcn_global_load_lds(
      (const __attribute__((address_space(1))) unsigned int*)gp,
      (__attribute__((address_space(3))) unsigned int*)lp, 16, 0, 0);
}

// premultiplied-mask accumulate: 84 VALU ops/element
__device__ __forceinline__ void acc_elem(float m, const float xre[6],
                                         const float xie[6], float accd[6],
                                         float accr[15], float acci[15]) {
  float yr[6], yz[6];
#pragma unroll
  for (int c = 0; c < 6; ++c) { yr[c] = m * xre[c]; yz[c] = m * xie[c]; }
#pragma unroll
  for (int c = 0; c < 6; ++c)
    accd[c] = fmaf(yr[c], xre[c], fmaf(yz[c], xie[c], accd[c]));
  int p = 0;
#pragma unroll
  for (int c = 0; c < 6; ++c) {
#pragma unroll
    for (int d2 = c + 1; d2 < 6; ++d2) {
      accr[p] = fmaf(yr[c], xre[d2], fmaf(yz[c], xie[d2], accr[p]));
      acci[p] = fmaf(yz[c], xre[d2], fmaf(-yr[c], xie[d2], acci[p]));
      ++p;
    }
  }
}

#define EXTRACT6(E, SRC, DST) \
  DST[0] = SRC[0].E; DST[1] = SRC[1].E; DST[2] = SRC[2].E; \
  DST[3] = SRC[3].E; DST[4] = SRC[4].E; DST[5] = SRC[5].E;

__global__ __launch_bounds__(128, 4) void cov_kernel(
    const float* __restrict__ Xre, const float* __restrict__ Xim,
    const float* __restrict__ masks, float* __restrict__ cov) {
  // sh[buf][stream][64 float4]: streams 0-5 Xre, 6-11 Xim, 12 mask(s=0),
  // 13 mask(s=1). 3 buffers x 14 KB = 42 KB.
  __shared__ float4 sh[3][14][64];

  const int nwg = B_ * F_ * 3;               // 6144, %8==0 -> bijective
  const int cpx = nwg / 8;                   // 768 per XCD
  const int Bh = blockIdx.x;
  const int l = (Bh & 7) * cpx + (Bh >> 3);  // XCD-contiguous logical id
  const int bf = l / 3;
  const int i = l - bf * 3;
  const int b = bf / F_;
  const int f = bf - b * F_;
  const int s = threadIdx.x >> 6;            // wave id = s (0/1)
  const int lane = threadIdx.x & 63;
  const int j = s * 3 + i;                   // this wave's covariance set

  const size_t xb = (size_t)b * C_ * CH_ + (size_t)f * N_;

  // wave s stages 7 streams: s=0 -> X0..5 + mask(j=i); s=1 -> X6..11 + mask(3+i)
  const float4* gbase[7];
  int sid[7];
#pragma unroll
  for (int r = 0; r < 6; ++r) {
    const int st = s * 6 + r;                // 0..5 or 6..11
    const float* p = (st < 6) ? (Xre + xb + (size_t)st * CH_)
                              : (Xim + xb + (size_t)(st - 6) * CH_);
    gbase[r] = (const float4*)p;
    sid[r] = st;
  }
  gbase[6] = (const float4*)(masks + ((size_t)b * 6 + j) * CH_ + (size_t)f * N_);
  sid[6] = 12 + s;

  auto stage = [&](int bb, int ch) {
    int idx = ch * 64 + lane;
    if (idx >= NV4) idx = NV4 - 1;           // clamp; mask zeroed at consume
#pragma unroll
    for (int r = 0; r < 7; ++r)
      gld_lds16(gbase[r] + idx, &sh[bb][sid[r]][0]);
  };

  float accd[6] = {};
  float accr[15] = {};
  float acci[15] = {};

  stage(0, 0);   // 7 VMEM per wave in flight
  stage(1, 1);   // 14 in flight

#pragma unroll
  for (int ch = 0; ch < NCHUNK; ++ch) {
    const int bb = ch % 3;

    // own 7 of stage(ch) landed; stage(ch+1)'s 7 stay in flight (T4)
    if (ch < NCHUNK - 1) {
      asm volatile("s_waitcnt vmcnt(7)" ::: "memory");
    } else {
      asm volatile("s_waitcnt vmcnt(0)" ::: "memory");
    }
    // both waves' stage(ch) landed; both done computing ch-1
    __builtin_amdgcn_s_barrier();

    // prefetch ch+2 into buf[(ch+2)%3] == buf[(ch-1)%3] (free now)
    if (ch + 2 < NCHUNK) stage((ch + 2) % 3, ch + 2);

    // ---- consume chunk ch from LDS (13 ds_read_b128, conflict-free) ----
    float4 mm = sh[bb][12 + s][lane];
    float4 xr[6], xi[6];
#pragma unroll
    for (int c = 0; c < 6; ++c) {
      xr[c] = sh[bb][c][lane];
      xi[c] = sh[bb][6 + c][lane];
    }
    if (ch * 64 + lane >= NV4) mm = make_float4(0.f, 0.f, 0.f, 0.f);

    float xre[6], xie[6];
    EXTRACT6(x, xr, xre); EXTRACT6(x, xi, xie);
    acc_elem(mm.x, xre, xie, accd, accr, acci);
    EXTRACT6(y, xr, xre); EXTRACT6(y, xi, xie);
    acc_elem(mm.y, xre, xie, accd, accr, acci);
    EXTRACT6(z, xr, xre); EXTRACT6(z, xi, xie);
    acc_elem(mm.z, xre, xie, accd, accr, acci);
    EXTRACT6(w, xr, xre); EXTRACT6(w, xi, xie);
    acc_elem(mm.w, xre, xie, accd, accr, acci);
  }

  // deterministic 64-lane butterfly reduce
#pragma unroll
  for (int c = 0; c < 6; ++c) {
#pragma unroll
    for (int o = 32; o > 0; o >>= 1) accd[c] += __shfl_xor(accd[c], o, 64);
  }
#pragma unroll
  for (int p2 = 0; p2 < 15; ++p2) {
#pragma unroll
    for (int o = 32; o > 0; o >>= 1) {
      accr[p2] += __shfl_xor(accr[p2], o, 64);
      acci[p2] += __shfl_xor(acci[p2], o, 64);
    }
  }

  if (lane == 0) {
    float* o = cov + ((size_t)bf * 6 + j) * 36;   // layout solve expects
#pragma unroll
    for (int c = 0; c < 6; ++c) o[c] = accd[c];
#pragma unroll
    for (int p2 = 0; p2 < 15; ++p2) {
      o[6 + 2 * p2] = accr[p2];
      o[7 + 2 * p2] = acci[p2];
    }
  }
}

// ---------------------------------------------------------------------------
// Kernel 2 helpers (fp64, fully unrolled 6x6 complex linear algebra).
// ---------------------------------------------------------------------------
__device__ __forceinline__ void load_herm(const float* __restrict__ p,
                                          double* mr, double* mi) {
#pragma unroll
  for (int c = 0; c < 6; ++c) { mr[c * 6 + c] = (double)p[c]; mi[c * 6 + c] = 0.0; }
#pragma unroll
  for (int c = 0; c < 6; ++c) {
#pragma unroll
    for (int d = c + 1; d < 6; ++d) {
      const int pidx = 6 + 2 * ((11 - c) * c / 2 + (d - c - 1));
      double re = (double)p[pidx];
      double im = (double)p[pidx + 1];
      mr[c * 6 + d] = re;  mi[c * 6 + d] = im;
      mr[d * 6 + c] = re;  mi[d * 6 + c] = -im;
    }
  }
}

// Cholesky, lower triangle in place (reads lower+diag only). Diag real.
__device__ __forceinline__ void chol6(double* mr, double* mi) {
#pragma unroll
  for (int k = 0; k < 6; ++k) {
    double d = mr[k * 6 + k];
#pragma unroll
    for (int j = 0; j < 6; ++j) {
      if (j < k) d -= mr[k * 6 + j] * mr[k * 6 + j] + mi[k * 6 + j] * mi[k * 6 + j];
    }
    d = sqrt(fmax(d, 1e-300));
    mr[k * 6 + k] = d;  mi[k * 6 + k] = 0.0;
    double inv = 1.0 / d;
#pragma unroll
    for (int r = k + 1; r < 6; ++r) {
      double xre = mr[r * 6 + k], xim = mi[r * 6 + k];
#pragma unroll
      for (int j = 0; j < 6; ++j) {
        if (j < k) {
          double ar = mr[r * 6 + j], ai = mi[r * 6 + j];
          double br = mr[k * 6 + j], bi = mi[k * 6 + j];
          xre -= ar * br + ai * bi;     // L[r][j] * conj(L[k][j])
          xim -= ai * br - ar * bi;
        }
      }
      mr[r * 6 + k] = xre * inv;  mi[r * 6 + k] = xim * inv;
    }
  }
}

// forward (L y = rhs) then backward (L^H x = y), L lower in mr/mi.
__device__ __forceinline__ void chol_solve(const double* mr, const double* mi,
                                           double* xr, double* xi) {
  double yr[6], yi[6];
#pragma unroll
  for (int r = 0; r < 6; ++r) {
    double tr = xr[r], ti = xi[r];
#pragma unroll
    for (int k = 0; k < 6; ++k) {
      if (k < r) {
        double ar = mr[r * 6 + k], ai = mi[r * 6 + k];
        tr -= ar * yr[k] - ai * yi[k];
        ti -= ar * yi[k] + ai * yr[k];
      }
    }
    double inv = 1.0 / mr[r * 6 + r];
    yr[r] = tr * inv;  yi[r] = ti * inv;
  }
#pragma unroll
  for (int r = 5; r >= 0; --r) {
    double tr = yr[r], ti = yi[r];
#pragma unroll
    for (int k = 5; k >= 0; --k) {
      if (k > r) {
        double ar = mr[k * 6 + r], ai = -mi[k * 6 + r];  // conj(L[k][r])
        tr -= ar * xr[k] - ai * xi[k];
        ti -= ar * xi[k] + ai * xr[k];
      }
    }
    double inv = 1.0 / mr[r * 6 + r];
    xr[r] = tr * inv;  xi[r] = ti * inv;
  }
}

// ---------------------------------------------------------------------------
// Kernel 2: per-(b,s,f) GEVD rtf + MVDR weights, fp64, one thread per problem.
// ---------------------------------------------------------------------------
__global__ __launch_bounds__(64, 1) void solve_kernel(
    const float* __restrict__ cov, float* __restrict__ wts) {
  const int t = blockIdx.x * 64 + threadIdx.x;
  if (t >= B_ * S_ * F_) return;
  const int f = t % F_;
  const int s = (t / F_) % S_;
  const int b = t / (F_ * S_);
  const float* cb = cov + (((size_t)(b * F_ + f)) * 6 + s * 3) * 36;

  // --- L = chol(noise2 + load*I)
  double Lr[36], Li[36];
  load_herm(cb + 72, Lr, Li);
#pragma unroll
  for (int k = 0; k < 6; ++k) Lr[k * 6 + k] += LOAD_CONST;
  chol6(Lr, Li);

  // --- A = target covariance
  double Ar[36], Ai[36];
  load_herm(cb, Ar, Ai);

  // --- C = herm(L^{-1} A L^{-H}), upper+diag stored (diag imag = 0)
  double Cr[36], Ci[36];
#pragma unroll
  for (int k = 0; k < 36; ++k) { Cr[k] = 0.0; Ci[k] = 0.0; }
#pragma unroll
  for (int j = 0; j < 6; ++j) {
    // y = L^{-H} e_j
    double yr[6], yi[6];
#pragma unroll
    for (int r = 5; r >= 0; --r) {
      double tr = (r == j) ? 1.0 : 0.0, ti = 0.0;
#pragma unroll
      for (int k = 5; k >= 0; --k) {
        if (k > r) {
          double ar = Lr[k * 6 + r], ai = -Li[k * 6 + r];
          tr -= ar * yr[k] - ai * yi[k];
          ti -= ar * yi[k] + ai * yr[k];
        }
      }
      double inv = 1.0 / Lr[r * 6 + r];
      yr[r] = tr * inv;  yi[r] = ti * inv;
    }
    // z = A y
    double zr[6], zi[6];
#pragma unroll
    for (int r = 0; r < 6; ++r) {
      double tr = 0, ti = 0;
#pragma unroll
      for (int k = 0; k < 6; ++k) {
        double ar = Ar[r * 6 + k], ai = Ai[r * 6 + k];
        tr += ar * yr[k] - ai * yi[k];
        ti += ar * yi[k] + ai * yr[k];
      }
      zr[r] = tr;  zi[r] = ti;
    }
    // c_j = L^{-1} z
    double cr[6], ci2[6];
#pragma unroll
    for (int r = 0; r < 6; ++r) {
      double tr = zr[r], ti = zi[r];
#pragma unroll
      for (int k = 0; k < 6; ++k) {
        if (k < r) {
          double ar = Lr[r * 6 + k], ai = Li[r * 6 + k];
          tr -= ar * cr[k] - ai * ci2[k];
          ti -= ar * ci2[k] + ai * cr[k];
        }
      }
      double inv = 1.0 / Lr[r * 6 + r];
      cr[r] = tr * inv;  ci2[r] = ti * inv;
    }
    // hermitized accumulate: C = 0.5(C0 + C0^H)
#pragma unroll
    for (int r = 0; r < 6; ++r) {
      if (r < j)       { Cr[r * 6 + j] += 0.5 * cr[r];  Ci[r * 6 + j] += 0.5 * ci2[r]; }
      else if (r == j) { Cr[r * 6 + r] += cr[r]; }
      else             { Cr[j * 6 + r] += 0.5 * cr[r];  Ci[j * 6 + r] -= 0.5 * ci2[r]; }
    }
  }

  // --- keep original C for inverse iteration
  double Gr[36], Gi[36];
#pragma unroll
  for (int k = 0; k < 36; ++k) { Gr[k] = Cr[k]; Gi[k] = Ci[k]; }

  // --- eigenvalue-only cyclic Jacobi (8 sweeps) on compact Hermitian C
#pragma unroll
  for (int sweep = 0; sweep < 8; ++sweep) {
#pragma unroll
    for (int p = 0; p < 5; ++p) {
#pragma unroll
      for (int q = p + 1; q < 6; ++q) {
        double gr = Cr[p * 6 + q], gi = Ci[p * 6 + q];
        double g2 = gr * gr + gi * gi;
        if (g2 > 1e-26) {
          double g = sqrt(g2);
          double wr = gr / g, wi = -gi / g;          // w = e^{-i phi}
          double alpha = Cr[p * 6 + p], beta = Cr[q * 6 + q];
          double tau = (beta - alpha) / (2.0 * g);
          double tt = (tau >= 0.0 ? 1.0 : -1.0) / (fabs(tau) + sqrt(1.0 + tau * tau));
          double cc = 1.0 / sqrt(1.0 + tt * tt);
          double ss = tt * cc;
#pragma unroll
          for (int r = 0; r < 6; ++r) {
            if (r == p || r == q) continue;
            double rpr = (r < p) ? Cr[r * 6 + p] : Cr[p * 6 + r];
            double rpi = (r < p) ? Ci[r * 6 + p] : -Ci[p * 6 + r];
            double rqr = (r < q) ? Cr[r * 6 + q] : Cr[q * 6 + r];
            double rqi = (r < q) ? Ci[r * 6 + q] : -Ci[q * 6 + r];
            double wqr = wr * rqr - wi * rqi;        // w * a_rq
            double wqi = wr * rqi + wi * rqr;
            double nrpr = cc * rpr - ss * wqr;
            double nrpi = cc * rpi - ss * wqi;
            double nrqr = ss * rpr + cc * wqr;
            double nrqi = ss * rpi + cc * wqi;
            if (r < p) { Cr[r * 6 + p] = nrpr;  Ci[r * 6 + p] = nrpi; }
            else       { Cr[p * 6 + r] = nrpr;  Ci[p * 6 + r] = -nrpi; }
            if (r < q) { Cr[r * 6 + q] = nrqr;  Ci[r * 6 + q] = nrqi; }
            else       { Cr[q * 6 + r] = nrqr;  Ci[q * 6 + r] = -nrqi; }
          }
          Cr[p * 6 + p] = alpha - tt * g;
          Cr[q * 6 + q] = beta + tt * g;
          Cr[p * 6 + q] = 0.0;  Ci[p * 6 + q] = 0.0;
        }
      }
    }
  }

  double lmax = Cr[0];
  lmax = fmax(lmax, Cr[7]);  lmax = fmax(lmax, Cr[14]);
  lmax = fmax(lmax, Cr[21]); lmax = fmax(lmax, Cr[28]);
  lmax = fmax(lmax, Cr[35]);

  // --- M = shift*I - C_orig (PD), chol, 2x inverse iteration
  double Mr[36], Mi[36];
  double shift = lmax + fmax(1e-8 * fabs(lmax), 1e-30);
#pragma unroll
  for (int r = 0; r < 6; ++r) {
#pragma unroll
    for (int c = 0; c < 6; ++c) {
      double gre, gim;
      if (r == c)     { gre = Gr[r * 6 + c]; gim = 0.0; }
      else if (r < c) { gre = Gr[r * 6 + c]; gim = Gi[r * 6 + c]; }
      else            { gre = Gr[c * 6 + r]; gim = -Gi[c * 6 + r]; }
      Mr[r * 6 + c] = (r == c) ? (shift - gre) : -gre;
      Mi[r * 6 + c] = -gim;
    }
  }
  chol6(Mr, Mi);

  double ur[6] = {1.0, 0.8, -0.6, 1.1, -0.3, 0.5};
  double ui[6] = {0.2, -0.9, 0.7, 0.1, 1.0, -0.4};
#pragma unroll
  for (int it = 0; it < 2; ++it) {
    chol_solve(Mr, Mi, ur, ui);
    double nn = 0;
#pragma unroll
    for (int r = 0; r < 6; ++r) nn += ur[r] * ur[r] + ui[r] * ui[r];
    double innv = 1.0 / sqrt(fmax(nn, 1e-300));
#pragma unroll
    for (int r = 0; r < 6; ++r) { ur[r] *= innv; ui[r] *= innv; }
  }

  // --- v = L^{-H} u
  double vr[6], vi[6];
#pragma unroll
  for (int r = 5; r >= 0; --r) {
    double tr = ur[r], ti = ui[r];
#pragma unroll
    for (int k = 5; k >= 0; --k) {
      if (k > r) {
        double ar = Lr[k * 6 + r], ai = -Li[k * 6 + r];
        tr -= ar * vr[k] - ai * vi[k];
        ti -= ar * vi[k] + ai * vr[k];
      }
    }
    double inv = 1.0 / Lr[r * 6 + r];
    vr[r] = tr * inv;  vi[r] = ti * inv;
  }

  // --- rtf = v / v[0]
  double id2 = 1.0 / (vr[0] * vr[0] + vi[0] * vi[0]);
  double rtr[6], rti[6];
#pragma unroll
  for (int r = 0; r < 6; ++r) {
    rtr[r] = (vr[r] * vr[0] + vi[r] * vi[0]) * id2;
    rti[r] = (vi[r] * vr[0] - vr[r] * vi[0]) * id2;
  }

  // --- a = (noise1 + load*I)^{-1} rtf ; w = a / max(Re(rtf^H a), eps)
  load_herm(cb + 36, Mr, Mi);
#pragma unroll
  for (int k = 0; k < 6; ++k) Mr[k * 6 + k] += LOAD_CONST;
  chol6(Mr, Mi);
  double ar2[6], ai2[6];
#pragma unroll
  for (int r = 0; r < 6; ++r) { ar2[r] = rtr[r]; ai2[r] = rti[r]; }
  chol_solve(Mr, Mi, ar2, ai2);

  double denom = 0;
#pragma unroll
  for (int r = 0; r < 6; ++r) denom += rtr[r] * ar2[r] + rti[r] * ai2[r];
  denom = fmax(denom, EPS_DENOM_);
  double idn = 1.0 / denom;

  // store conj(w) in fp32: layout [b][s][f][c][re,im]
  float* wp = wts + (size_t)t * 12;
#pragma unroll
  for (int c = 0; c < 6; ++c) {
    wp[2 * c]     = (float)(ar2[c] * idn);
    wp[2 * c + 1] = (float)(-ai2[c] * idn);
  }
}

// ---------------------------------------------------------------------------
// Kernel 3: Y[b,s,f,n] = sum_c X[b,c,f,n] * wconj[b,s,f,c]; out (B,S,F,N,2)
// float4 over n, plain float4 components (no unions).
// ---------------------------------------------------------------------------
__global__ __launch_bounds__(256) void bf_kernel(
    const float* __restrict__ Xre, const float* __restrict__ Xim,
    const float* __restrict__ wts, float* __restrict__ out) {
  const int blk = blockIdx.x;
  const int b = blk / F_;
  const int f = blk - b * F_;
  const size_t xb = (size_t)b * C_ * CH_ + (size_t)f * N_;

  float wr[2][6], wi[2][6];
#pragma unroll
  for (int s = 0; s < 2; ++s) {
    const float* wp = wts + (((size_t)(b * S_ + s)) * F_ + f) * 12;
#pragma unroll
    for (int c = 0; c < 6; ++c) { wr[s][c] = wp[2 * c]; wi[s][c] = wp[2 * c + 1]; }
  }
  float4* o0 = (float4*)(out + ((size_t)(b * S_ + 0) * F_ + f) * N_ * 2);
  float4* o1 = (float4*)(out + ((size_t)(b * S_ + 1) * F_ + f) * N_ * 2);

  const int NV = N_ / 4;  // 500
  for (int n4 = threadIdx.x; n4 < NV; n4 += 256) {
    float4 xr[6], xi[6];
#pragma unroll
    for (int c = 0; c < 6; ++c) {
      xr[c] = ((const float4*)(Xre + xb + (size_t)c * CH_))[n4];
      xi[c] = ((const float4*)(Xim + xb + (size_t)c * CH_))[n4];
    }
#pragma unroll
    for (int s = 0; s < 2; ++s) {
      float yrx = 0.f, yix = 0.f, yry = 0.f, yiy = 0.f;
      float yrz = 0.f, yiz = 0.f, yrw = 0.f, yiw = 0.f;
#pragma unroll
      for (int c = 0; c < 6; ++c) {
        const float WR = wr[s][c], WI = wi[s][c];
        yrx = fmaf(xr[c].x, WR, fmaf(-xi[c].x, WI, yrx));
        yix = fmaf(xr[c].x, WI, fmaf(xi[c].x, WR, yix));
        yry = fmaf(xr[c].y, WR, fmaf(-xi[c].y, WI, yry));
        yiy = fmaf(xr[c].y, WI, fmaf(xi[c].y, WR, yiy));
        yrz = fmaf(xr[c].z, WR, fmaf(-xi[c].z, WI, yrz));
        yiz = fmaf(xr[c].z, WI, fmaf(xi[c].z, WR, yiz));
        yrw = fmaf(xr[c].w, WR, fmaf(-xi[c].w, WI, yrw));
        yiw = fmaf(xr[c].w, WI, fmaf(xi[c].w, WR, yiw));
      }
      float4* op = s ? o1 : o0;
      op[2 * n4]     = make_float4(yrx, yix, yry, yiy);
      op[2 * n4 + 1] = make_float4(yrz, yiz, yrw, yiw);
    }
  }
}

// ---------------------------------------------------------------------------
extern "C" void kernel_launch(void* const* d_in, const int* in_sizes, int n_in,
                              void* d_out, int out_size, void* d_ws, size_t ws_size,
                              hipStream_t stream) {
  const float* Xre   = (const float*)d_in[0];
  const float* Xim   = (const float*)d_in[1];
  const float* masks = (const float*)d_in[2];
  float* out = (float*)d_out;

  float* cov = (float*)d_ws;                              // 2048*6*36 floats
  float* wts = cov + (size_t)B_ * F_ * 6 * 36;            // 4096*12 floats

  cov_kernel<<<B_ * F_ * 3, 128, 0, stream>>>(Xre, Xim, masks, cov);
  solve_kernel<<<(B_ * S_ * F_ + 63) / 64, 64, 0, stream>>>(cov, wts);
  bf_kernel<<<B_ * F_, 256, 0, stream>>>(Xre, Xim, wts, out);
}

// Round 13
// 218.115 us; speedup vs baseline: 1.2410x; 1.2410x over previous
//
#include <hip/hip_runtime.h>

#define B_ 4
#define S_ 2
#define C_ 6
#define F_ 512
#define N_ 2000
#define CH_ (F_ * N_)          // stride between channels / mask slices
#define LOAD_CONST 1e-5
#define EPS_DENOM_ 1e-6
#define NV4 (N_ / 4)           // 500 float4 per stream
#define NCHUNK 8

// ---------------------------------------------------------------------------
// Kernel 1: masked covariances — one wave per (bf,i) computes BOTH s-sets.
// r12 post-mortem: barrier-coupled 2-wave LDS sharing collapsed occupancy ->
// 5.7 B/cy/CU. r10 precedent: barrier-free wave-private LDS + counted vmcnt
// sustains the ~14 B/cy/CU L2->CU path cap even at 6 waves/CU. So: keep the
// r10 structure, halve PATH BYTES by computing 2 sets per wave (72 acc regs).
// 14 streams (12 X + 2 masks) double-buffered, vmcnt(14) counted (T4).
// Consume = scalar ds_read_b32 at float offset lane+64e -> 2 lanes/bank =
// conflict-free (m136); live regs ~95 (72 acc + 14 scalars) -> no spill.
// Products x_c*x_d shared across both masks: 144 ops/elem for 2 sets.
// XCD-bijective swizzle: 3 i-siblings of a (b,f) on one XCD (r9: FETCH
// 670->150 MB verified).
// ---------------------------------------------------------------------------
__device__ __forceinline__ void gld_lds16(const void* gp, void* lp) {
  __builtin_amdgcn_global_load_lds(
      (const __attribute__((address_space(1))) unsigned int*)gp,
      (__attribute__((address_space(3))) unsigned int*)lp, 16, 0, 0);
}

__global__ __launch_bounds__(64, 2) void cov_kernel(
    const float* __restrict__ Xre, const float* __restrict__ Xim,
    const float* __restrict__ masks, float* __restrict__ cov) {
  // sh[buf][stream][256 floats]: streams 0-5 Xre, 6-11 Xim, 12 mask(s=0,j=i),
  // 13 mask(s=1,j=3+i). 2 x 14 x 1KB = 28 KB, wave-private.
  __shared__ float sh[2][14][256];

  const int nwg = B_ * F_ * 3;               // 6144, %8==0 -> bijective
  const int cpx = nwg / 8;                   // 768 per XCD
  const int Bh = blockIdx.x;
  const int l = (Bh & 7) * cpx + (Bh >> 3);  // XCD-contiguous logical id
  const int bf = l / 3;
  const int i = l - bf * 3;
  const int b = bf / F_;
  const int f = bf - b * F_;
  const int lane = threadIdx.x;              // 0..63

  const size_t xb = (size_t)b * C_ * CH_ + (size_t)f * N_;

  const float4* gbase[14];
#pragma unroll
  for (int st = 0; st < 12; ++st) {
    const float* p = (st < 6) ? (Xre + xb + (size_t)st * CH_)
                              : (Xim + xb + (size_t)(st - 6) * CH_);
    gbase[st] = (const float4*)p;
  }
  gbase[12] = (const float4*)(masks + ((size_t)b * 6 + i) * CH_ + (size_t)f * N_);
  gbase[13] = (const float4*)(masks + ((size_t)b * 6 + 3 + i) * CH_ + (size_t)f * N_);

  // stage chunk ch into buffer bb: 14 x global_load_lds (1KB each)
  auto stage = [&](int bb, int ch) {
    int idx = ch * 64 + lane;
    if (idx >= NV4) idx = NV4 - 1;           // clamp; masks zeroed at consume
#pragma unroll
    for (int st = 0; st < 14; ++st)
      gld_lds16(gbase[st] + idx, &sh[bb][st][0]);
  };

  float acc0d[6] = {}, acc0r[15] = {}, acc0i[15] = {};
  float acc1d[6] = {}, acc1r[15] = {}, acc1i[15] = {};

  stage(0, 0);   // 14 VMEM in flight
  stage(1, 1);   // 28 in flight

  for (int ch = 0; ch < NCHUNK; ++ch) {
    const int bb = ch & 1;

    // own stage(ch) landed; stage(ch+1)'s 14 ops stay in flight (T4)
    if (ch < NCHUNK - 1) {
      asm volatile("s_waitcnt vmcnt(14)" ::: "memory");
    } else {
      asm volatile("s_waitcnt vmcnt(0)" ::: "memory");
    }

    // ---- consume 256 elements: 4 e-groups of scalar ds reads + compute ----
#pragma unroll
    for (int e = 0; e < 4; ++e) {
      const int fo = lane + 64 * e;          // float offset in row (0..255)
      float xre[6], xie[6];
#pragma unroll
      for (int c = 0; c < 6; ++c) {
        xre[c] = sh[bb][c][fo];
        xie[c] = sh[bb][6 + c][fo];
      }
      float m0 = sh[bb][12][fo];
      float m1 = sh[bb][13][fo];
      if (ch * 256 + fo >= N_) { m0 = 0.f; m1 = 0.f; }

      // shared products, two mask-weighted accumulations
#pragma unroll
      for (int c = 0; c < 6; ++c) {
        const float d = fmaf(xre[c], xre[c], xie[c] * xie[c]);
        acc0d[c] = fmaf(m0, d, acc0d[c]);
        acc1d[c] = fmaf(m1, d, acc1d[c]);
      }
      int p = 0;
#pragma unroll
      for (int c = 0; c < 6; ++c) {
#pragma unroll
        for (int d2 = c + 1; d2 < 6; ++d2) {
          const float pr = fmaf(xre[c], xre[d2], xie[c] * xie[d2]);
          const float pi = fmaf(xie[c], xre[d2], -(xre[c] * xie[d2]));
          acc0r[p] = fmaf(m0, pr, acc0r[p]);
          acc0i[p] = fmaf(m0, pi, acc0i[p]);
          acc1r[p] = fmaf(m1, pr, acc1r[p]);
          acc1i[p] = fmaf(m1, pi, acc1i[p]);
          ++p;
        }
      }
    }

    // all ds reads of this buffer retired before overwriting it
    asm volatile("s_waitcnt lgkmcnt(0)" ::: "memory");
    if (ch + 2 < NCHUNK) stage(bb, ch + 2);
  }

  // deterministic 64-lane butterfly reduce (both sets)
#pragma unroll
  for (int c = 0; c < 6; ++c) {
#pragma unroll
    for (int o = 32; o > 0; o >>= 1) {
      acc0d[c] += __shfl_xor(acc0d[c], o, 64);
      acc1d[c] += __shfl_xor(acc1d[c], o, 64);
    }
  }
#pragma unroll
  for (int p2 = 0; p2 < 15; ++p2) {
#pragma unroll
    for (int o = 32; o > 0; o >>= 1) {
      acc0r[p2] += __shfl_xor(acc0r[p2], o, 64);
      acc0i[p2] += __shfl_xor(acc0i[p2], o, 64);
      acc1r[p2] += __shfl_xor(acc1r[p2], o, 64);
      acc1i[p2] += __shfl_xor(acc1i[p2], o, 64);
    }
  }

  if (lane == 0) {
    float* o0 = cov + ((size_t)bf * 6 + i) * 36;       // set j = i   (s=0)
    float* o1 = cov + ((size_t)bf * 6 + 3 + i) * 36;   // set j = 3+i (s=1)
#pragma unroll
    for (int c = 0; c < 6; ++c) { o0[c] = acc0d[c]; o1[c] = acc1d[c]; }
#pragma unroll
    for (int p2 = 0; p2 < 15; ++p2) {
      o0[6 + 2 * p2] = acc0r[p2];  o0[7 + 2 * p2] = acc0i[p2];
      o1[6 + 2 * p2] = acc1r[p2];  o1[7 + 2 * p2] = acc1i[p2];
    }
  }
}

// ---------------------------------------------------------------------------
// Kernel 2 helpers (fp64, fully unrolled 6x6 complex linear algebra).
// ---------------------------------------------------------------------------
__device__ __forceinline__ void load_herm(const float* __restrict__ p,
                                          double* mr, double* mi) {
#pragma unroll
  for (int c = 0; c < 6; ++c) { mr[c * 6 + c] = (double)p[c]; mi[c * 6 + c] = 0.0; }
#pragma unroll
  for (int c = 0; c < 6; ++c) {
#pragma unroll
    for (int d = c + 1; d < 6; ++d) {
      const int pidx = 6 + 2 * ((11 - c) * c / 2 + (d - c - 1));
      double re = (double)p[pidx];
      double im = (double)p[pidx + 1];
      mr[c * 6 + d] = re;  mi[c * 6 + d] = im;
      mr[d * 6 + c] = re;  mi[d * 6 + c] = -im;
    }
  }
}

// Cholesky, lower triangle in place (reads lower+diag only). Diag real.
__device__ __forceinline__ void chol6(double* mr, double* mi) {
#pragma unroll
  for (int k = 0; k < 6; ++k) {
    double d = mr[k * 6 + k];
#pragma unroll
    for (int j = 0; j < 6; ++j) {
      if (j < k) d -= mr[k * 6 + j] * mr[k * 6 + j] + mi[k * 6 + j] * mi[k * 6 + j];
    }
    d = sqrt(fmax(d, 1e-300));
    mr[k * 6 + k] = d;  mi[k * 6 + k] = 0.0;
    double inv = 1.0 / d;
#pragma unroll
    for (int r = k + 1; r < 6; ++r) {
      double xre = mr[r * 6 + k], xim = mi[r * 6 + k];
#pragma unroll
      for (int j = 0; j < 6; ++j) {
        if (j < k) {
          double ar = mr[r * 6 + j], ai = mi[r * 6 + j];
          double br = mr[k * 6 + j], bi = mi[k * 6 + j];
          xre -= ar * br + ai * bi;     // L[r][j] * conj(L[k][j])
          xim -= ai * br - ar * bi;
        }
      }
      mr[r * 6 + k] = xre * inv;  mi[r * 6 + k] = xim * inv;
    }
  }
}

// forward (L y = rhs) then backward (L^H x = y), L lower in mr/mi.
__device__ __forceinline__ void chol_solve(const double* mr, const double* mi,
                                           double* xr, double* xi) {
  double yr[6], yi[6];
#pragma unroll
  for (int r = 0; r < 6; ++r) {
    double tr = xr[r], ti = xi[r];
#pragma unroll
    for (int k = 0; k < 6; ++k) {
      if (k < r) {
        double ar = mr[r * 6 + k], ai = mi[r * 6 + k];
        tr -= ar * yr[k] - ai * yi[k];
        ti -= ar * yi[k] + ai * yr[k];
      }
    }
    double inv = 1.0 / mr[r * 6 + r];
    yr[r] = tr * inv;  yi[r] = ti * inv;
  }
#pragma unroll
  for (int r = 5; r >= 0; --r) {
    double tr = yr[r], ti = yi[r];
#pragma unroll
    for (int k = 5; k >= 0; --k) {
      if (k > r) {
        double ar = mr[k * 6 + r], ai = -mi[k * 6 + r];  // conj(L[k][r])
        tr -= ar * xr[k] - ai * xi[k];
        ti -= ar * xi[k] + ai * xr[k];
      }
    }
    double inv = 1.0 / mr[r * 6 + r];
    xr[r] = tr * inv;  xi[r] = ti * inv;
  }
}

// ---------------------------------------------------------------------------
// Kernel 2: per-(b,s,f) GEVD rtf + MVDR weights, fp64, one thread per problem.
// ---------------------------------------------------------------------------
__global__ __launch_bounds__(64, 1) void solve_kernel(
    const float* __restrict__ cov, float* __restrict__ wts) {
  const int t = blockIdx.x * 64 + threadIdx.x;
  if (t >= B_ * S_ * F_) return;
  const int f = t % F_;
  const int s = (t / F_) % S_;
  const int b = t / (F_ * S_);
  const float* cb = cov + (((size_t)(b * F_ + f)) * 6 + s * 3) * 36;

  // --- L = chol(noise2 + load*I)
  double Lr[36], Li[36];
  load_herm(cb + 72, Lr, Li);
#pragma unroll
  for (int k = 0; k < 6; ++k) Lr[k * 6 + k] += LOAD_CONST;
  chol6(Lr, Li);

  // --- A = target covariance
  double Ar[36], Ai[36];
  load_herm(cb, Ar, Ai);

  // --- C = herm(L^{-1} A L^{-H}), upper+diag stored (diag imag = 0)
  double Cr[36], Ci[36];
#pragma unroll
  for (int k = 0; k < 36; ++k) { Cr[k] = 0.0; Ci[k] = 0.0; }
#pragma unroll
  for (int j = 0; j < 6; ++j) {
    // y = L^{-H} e_j
    double yr[6], yi[6];
#pragma unroll
    for (int r = 5; r >= 0; --r) {
      double tr = (r == j) ? 1.0 : 0.0, ti = 0.0;
#pragma unroll
      for (int k = 5; k >= 0; --k) {
        if (k > r) {
          double ar = Lr[k * 6 + r], ai = -Li[k * 6 + r];
          tr -= ar * yr[k] - ai * yi[k];
          ti -= ar * yi[k] + ai * yr[k];
        }
      }
      double inv = 1.0 / Lr[r * 6 + r];
      yr[r] = tr * inv;  yi[r] = ti * inv;
    }
    // z = A y
    double zr[6], zi[6];
#pragma unroll
    for (int r = 0; r < 6; ++r) {
      double tr = 0, ti = 0;
#pragma unroll
      for (int k = 0; k < 6; ++k) {
        double ar = Ar[r * 6 + k], ai = Ai[r * 6 + k];
        tr += ar * yr[k] - ai * yi[k];
        ti += ar * yi[k] + ai * yr[k];
      }
      zr[r] = tr;  zi[r] = ti;
    }
    // c_j = L^{-1} z
    double cr[6], ci2[6];
#pragma unroll
    for (int r = 0; r < 6; ++r) {
      double tr = zr[r], ti = zi[r];
#pragma unroll
      for (int k = 0; k < 6; ++k) {
        if (k < r) {
          double ar = Lr[r * 6 + k], ai = Li[r * 6 + k];
          tr -= ar * cr[k] - ai * ci2[k];
          ti -= ar * ci2[k] + ai * cr[k];
        }
      }
      double inv = 1.0 / Lr[r * 6 + r];
      cr[r] = tr * inv;  ci2[r] = ti * inv;
    }
    // hermitized accumulate: C = 0.5(C0 + C0^H)
#pragma unroll
    for (int r = 0; r < 6; ++r) {
      if (r < j)       { Cr[r * 6 + j] += 0.5 * cr[r];  Ci[r * 6 + j] += 0.5 * ci2[r]; }
      else if (r == j) { Cr[r * 6 + r] += cr[r]; }
      else             { Cr[j * 6 + r] += 0.5 * cr[r];  Ci[j * 6 + r] -= 0.5 * ci2[r]; }
    }
  }

  // --- keep original C for inverse iteration
  double Gr[36], Gi[36];
#pragma unroll
  for (int k = 0; k < 36; ++k) { Gr[k] = Cr[k]; Gi[k] = Ci[k]; }

  // --- eigenvalue-only cyclic Jacobi (8 sweeps) on compact Hermitian C
#pragma unroll
  for (int sweep = 0; sweep < 8; ++sweep) {
#pragma unroll
    for (int p = 0; p < 5; ++p) {
#pragma unroll
      for (int q = p + 1; q < 6; ++q) {
        double gr = Cr[p * 6 + q], gi = Ci[p * 6 + q];
        double g2 = gr * gr + gi * gi;
        if (g2 > 1e-26) {
          double g = sqrt(g2);
          double wr = gr / g, wi = -gi / g;          // w = e^{-i phi}
          double alpha = Cr[p * 6 + p], beta = Cr[q * 6 + q];
          double tau = (beta - alpha) / (2.0 * g);
          double tt = (tau >= 0.0 ? 1.0 : -1.0) / (fabs(tau) + sqrt(1.0 + tau * tau));
          double cc = 1.0 / sqrt(1.0 + tt * tt);
          double ss = tt * cc;
#pragma unroll
          for (int r = 0; r < 6; ++r) {
            if (r == p || r == q) continue;
            double rpr = (r < p) ? Cr[r * 6 + p] : Cr[p * 6 + r];
            double rpi = (r < p) ? Ci[r * 6 + p] : -Ci[p * 6 + r];
            double rqr = (r < q) ? Cr[r * 6 + q] : Cr[q * 6 + r];
            double rqi = (r < q) ? Ci[r * 6 + q] : -Ci[q * 6 + r];
            double wqr = wr * rqr - wi * rqi;        // w * a_rq
            double wqi = wr * rqi + wi * rqr;
            double nrpr = cc * rpr - ss * wqr;
            double nrpi = cc * rpi - ss * wqi;
            double nrqr = ss * rpr + cc * wqr;
            double nrqi = ss * rpi + cc * wqi;
            if (r < p) { Cr[r * 6 + p] = nrpr;  Ci[r * 6 + p] = nrpi; }
            else       { Cr[p * 6 + r] = nrpr;  Ci[p * 6 + r] = -nrpi; }
            if (r < q) { Cr[r * 6 + q] = nrqr;  Ci[r * 6 + q] = nrqi; }
            else       { Cr[q * 6 + r] = nrqr;  Ci[q * 6 + r] = -nrqi; }
          }
          Cr[p * 6 + p] = alpha - tt * g;
          Cr[q * 6 + q] = beta + tt * g;
          Cr[p * 6 + q] = 0.0;  Ci[p * 6 + q] = 0.0;
        }
      }
    }
  }

  double lmax = Cr[0];
  lmax = fmax(lmax, Cr[7]);  lmax = fmax(lmax, Cr[14]);
  lmax = fmax(lmax, Cr[21]); lmax = fmax(lmax, Cr[28]);
  lmax = fmax(lmax, Cr[35]);

  // --- M = shift*I - C_orig (PD), chol, 2x inverse iteration
  double Mr[36], Mi[36];
  double shift = lmax + fmax(1e-8 * fabs(lmax), 1e-30);
#pragma unroll
  for (int r = 0; r < 6; ++r) {
#pragma unroll
    for (int c = 0; c < 6; ++c) {
      double gre, gim;
      if (r == c)     { gre = Gr[r * 6 + c]; gim = 0.0; }
      else if (r < c) { gre = Gr[r * 6 + c]; gim = Gi[r * 6 + c]; }
      else            { gre = Gr[c * 6 + r]; gim = -Gi[c * 6 + r]; }
      Mr[r * 6 + c] = (r == c) ? (shift - gre) : -gre;
      Mi[r * 6 + c] = -gim;
    }
  }
  chol6(Mr, Mi);

  double ur[6] = {1.0, 0.8, -0.6, 1.1, -0.3, 0.5};
  double ui[6] = {0.2, -0.9, 0.7, 0.1, 1.0, -0.4};
#pragma unroll
  for (int it = 0; it < 2; ++it) {
    chol_solve(Mr, Mi, ur, ui);
    double nn = 0;
#pragma unroll
    for (int r = 0; r < 6; ++r) nn += ur[r] * ur[r] + ui[r] * ui[r];
    double innv = 1.0 / sqrt(fmax(nn, 1e-300));
#pragma unroll
    for (int r = 0; r < 6; ++r) { ur[r] *= innv; ui[r] *= innv; }
  }

  // --- v = L^{-H} u
  double vr[6], vi[6];
#pragma unroll
  for (int r = 5; r >= 0; --r) {
    double tr = ur[r], ti = ui[r];
#pragma unroll
    for (int k = 5; k >= 0; --k) {
      if (k > r) {
        double ar = Lr[k * 6 + r], ai = -Li[k * 6 + r];
        tr -= ar * vr[k] - ai * vi[k];
        ti -= ar * vi[k] + ai * vr[k];
      }
    }
    double inv = 1.0 / Lr[r * 6 + r];
    vr[r] = tr * inv;  vi[r] = ti * inv;
  }

  // --- rtf = v / v[0]
  double id2 = 1.0 / (vr[0] * vr[0] + vi[0] * vi[0]);
  double rtr[6], rti[6];
#pragma unroll
  for (int r = 0; r < 6; ++r) {
    rtr[r] = (vr[r] * vr[0] + vi[r] * vi[0]) * id2;
    rti[r] = (vi[r] * vr[0] - vr[r] * vi[0]) * id2;
  }

  // --- a = (noise1 + load*I)^{-1} rtf ; w = a / max(Re(rtf^H a), eps)
  load_herm(cb + 36, Mr, Mi);
#pragma unroll
  for (int k = 0; k < 6; ++k) Mr[k * 6 + k] += LOAD_CONST;
  chol6(Mr, Mi);
  double ar2[6], ai2[6];
#pragma unroll
  for (int r = 0; r < 6; ++r) { ar2[r] = rtr[r]; ai2[r] = rti[r]; }
  chol_solve(Mr, Mi, ar2, ai2);

  double denom = 0;
#pragma unroll
  for (int r = 0; r < 6; ++r) denom += rtr[r] * ar2[r] + rti[r] * ai2[r];
  denom = fmax(denom, EPS_DENOM_);
  double idn = 1.0 / denom;

  // store conj(w) in fp32: layout [b][s][f][c][re,im]
  float* wp = wts + (size_t)t * 12;
#pragma unroll
  for (int c = 0; c < 6; ++c) {
    wp[2 * c]     = (float)(ar2[c] * idn);
    wp[2 * c + 1] = (float)(-ai2[c] * idn);
  }
}

// ---------------------------------------------------------------------------
// Kernel 3: Y[b,s,f,n] = sum_c X[b,c,f,n] * wconj[b,s,f,c]; out (B,S,F,N,2)
// float4 over n, plain float4 components (no unions).
// ---------------------------------------------------------------------------
__global__ __launch_bounds__(256) void bf_kernel(
    const float* __restrict__ Xre, const float* __restrict__ Xim,
    const float* __restrict__ wts, float* __restrict__ out) {
  const int blk = blockIdx.x;
  const int b = blk / F_;
  const int f = blk - b * F_;
  const size_t xb = (size_t)b * C_ * CH_ + (size_t)f * N_;

  float wr[2][6], wi[2][6];
#pragma unroll
  for (int s = 0; s < 2; ++s) {
    const float* wp = wts + (((size_t)(b * S_ + s)) * F_ + f) * 12;
#pragma unroll
    for (int c = 0; c < 6; ++c) { wr[s][c] = wp[2 * c]; wi[s][c] = wp[2 * c + 1]; }
  }
  float4* o0 = (float4*)(out + ((size_t)(b * S_ + 0) * F_ + f) * N_ * 2);
  float4* o1 = (float4*)(out + ((size_t)(b * S_ + 1) * F_ + f) * N_ * 2);

  const int NV = N_ / 4;  // 500
  for (int n4 = threadIdx.x; n4 < NV; n4 += 256) {
    float4 xr[6], xi[6];
#pragma unroll
    for (int c = 0; c < 6; ++c) {
      xr[c] = ((const float4*)(Xre + xb + (size_t)c * CH_))[n4];
      xi[c] = ((const float4*)(Xim + xb + (size_t)c * CH_))[n4];
    }
#pragma unroll
    for (int s = 0; s < 2; ++s) {
      float yrx = 0.f, yix = 0.f, yry = 0.f, yiy = 0.f;
      float yrz = 0.f, yiz = 0.f, yrw = 0.f, yiw = 0.f;
#pragma unroll
      for (int c = 0; c < 6; ++c) {
        const float WR = wr[s][c], WI = wi[s][c];
        yrx = fmaf(xr[c].x, WR, fmaf(-xi[c].x, WI, yrx));
        yix = fmaf(xr[c].x, WI, fmaf(xi[c].x, WR, yix));
        yry = fmaf(xr[c].y, WR, fmaf(-xi[c].y, WI, yry));
        yiy = fmaf(xr[c].y, WI, fmaf(xi[c].y, WR, yiy));
        yrz = fmaf(xr[c].z, WR, fmaf(-xi[c].z, WI, yrz));
        yiz = fmaf(xr[c].z, WI, fmaf(xi[c].z, WR, yiz));
        yrw = fmaf(xr[c].w, WR, fmaf(-xi[c].w, WI, yrw));
        yiw = fmaf(xr[c].w, WI, fmaf(xi[c].w, WR, yiw));
      }
      float4* op = s ? o1 : o0;
      op[2 * n4]     = make_float4(yrx, yix, yry, yiy);
      op[2 * n4 + 1] = make_float4(yrz, yiz, yrw, yiw);
    }
  }
}

// ---------------------------------------------------------------------------
extern "C" void kernel_launch(void* const* d_in, const int* in_sizes, int n_in,
                              void* d_out, int out_size, void* d_ws, size_t ws_size,
                              hipStream_t stream) {
  const float* Xre   = (const float*)d_in[0];
  const float* Xim   = (const float*)d_in[1];
  const float* masks = (const float*)d_in[2];
  float* out = (float*)d_out;

  float* cov = (float*)d_ws;                              // 2048*6*36 floats
  float* wts = cov + (size_t)B_ * F_ * 6 * 36;            // 4096*12 floats

  cov_kernel<<<B_ * F_ * 3, 64, 0, stream>>>(Xre, Xim, masks, cov);
  solve_kernel<<<(B_ * S_ * F_ + 63) / 64, 64, 0, stream>>>(cov, wts);
  bf_kernel<<<B_ * F_, 256, 0, stream>>>(Xre, Xim, wts, out);
}